// Round 12
// baseline (217.426 us; speedup 1.0000x reference)
//
#include <hip/hip_runtime.h>
#include <hip/hip_bf16.h>

#define IN_F 1024
#define OUT_F 1024
#define KTOT (IN_F * 9)   // 9216: channel-major, k = c*1024 + i, c=0 is silu
#define M_ROWS 8192

#define BK 64
#define NT (KTOT / BK)    // 144 K-tiles total; 72 per K-half
#define NT_H (NT / 2)

#define A_TILE_E 16384    // elements per A K-tile of a 256-row panel (32 KB)
#define B_TILE_E 8192     // elements per B K-tile of a 128-col panel (16 KB)

typedef short bf16x8 __attribute__((ext_vector_type(8)));
typedef int   i32x4  __attribute__((ext_vector_type(4)));
typedef float f32x4  __attribute__((ext_vector_type(4)));

#define AS1 __attribute__((address_space(1)))
#define AS3 __attribute__((address_space(3)))

// ---------------------------------------------------------------- basis eval
__device__ __forceinline__ void kan_basis_fast(
    float xv, const float* __restrict__ g,
    const float* __restrict__ inv1, const float* __restrict__ inv2,
    const float* __restrict__ inv3, float* __restrict__ out) {
  float b[11];
#pragma unroll
  for (int j = 0; j < 11; ++j)
    b[j] = (xv >= g[j] && xv < g[j + 1]) ? 1.0f : 0.0f;
#pragma unroll
  for (int j = 0; j < 10; ++j)
    b[j] = (xv - g[j]) * inv1[j] * b[j] + (g[j + 2] - xv) * inv1[j + 1] * b[j + 1];
#pragma unroll
  for (int j = 0; j < 9; ++j)
    b[j] = (xv - g[j]) * inv2[j] * b[j] + (g[j + 3] - xv) * inv2[j + 1] * b[j + 1];
#pragma unroll
  for (int j = 0; j < 8; ++j)
    b[j] = (xv - g[j]) * inv3[j] * b[j] + (g[j + 4] - xv) * inv3[j + 1] * b[j + 1];
#pragma unroll
  for (int j = 0; j < 8; ++j) out[j] = b[j];
}

// ------------------------------------------------- A expansion (fp32 -> bf16)
// Frag-ordered A (verified R9-R11): frag = (((bm*NT+kt)*4+wm4)*4+m)*2+kk,
// lane = lhi*16+l15 holds A[row][k=kt*64+kk*32+lhi*8+j]; 16-row groups
// g = wm4*4+m cover rows g*16..g*16+15 of the 256-row panel bm.
__global__ __launch_bounds__(256) void expand_a(
    const float* __restrict__ x, const float* __restrict__ grid,
    __hip_bfloat16* __restrict__ A, int row0, int nrows) {
  const int tid = threadIdx.x;
  const int lane = tid & 63;
  const int wvx = tid >> 6;            // 0..3 : i-subblock
  const int l15 = lane & 15;
  const int lhi = lane >> 4;

  const int nb = blockIdx.x >> 3;      // 16-row group (local)
  const int ib = blockIdx.x & 7;       // 128-wide i group
  const int n_l = nb * 16 + l15;       // local row
  const int i0 = ib * 128 + wvx * 32 + lhi * 8;

  const int bm = n_l >> 8, wm = (n_l >> 6) & 3, m = (n_l >> 4) & 3;

  float g[12];
  const float* gp = grid + (size_t)i0 * 12;   // rows identical by construction
#pragma unroll
  for (int j = 0; j < 12; ++j) g[j] = gp[j];
  float inv1[11], inv2[10], inv3[9];
#pragma unroll
  for (int j = 0; j < 11; ++j) inv1[j] = 1.0f / (g[j + 1] - g[j]);
#pragma unroll
  for (int j = 0; j < 10; ++j) inv2[j] = 1.0f / (g[j + 2] - g[j]);
#pragma unroll
  for (int j = 0; j < 9; ++j)  inv3[j] = 1.0f / (g[j + 3] - g[j]);

  const float* xp = x + (size_t)(row0 + n_l) * IN_F + i0;
  float xs[8];
  *(f32x4*)&xs[0] = *(const f32x4*)xp;
  *(f32x4*)&xs[4] = *(const f32x4*)(xp + 4);

  bf16x8 out[9];
#pragma unroll
  for (int j = 0; j < 8; ++j) {
    float xv = xs[j];
    float bas[8];
    kan_basis_fast(xv, g, inv1, inv2, inv3, bas);
    float s = xv / (1.0f + __expf(-xv));
    out[0][j] = (short)__bfloat16_as_ushort(__float2bfloat16(s));
#pragma unroll
    for (int c = 0; c < 8; ++c)
      out[c + 1][j] = (short)__bfloat16_as_ushort(__float2bfloat16(bas[c]));
  }

#pragma unroll
  for (int c = 0; c < 9; ++c) {
    int k0 = c * IN_F + i0;            // wave-uniform kt,kk per c
    int kt = k0 >> 6;
    int kk = (k0 >> 5) & 1;
    size_t frag = ((((size_t)bm * NT + kt) * 4 + wm) * 4 + m) * 2 + kk;
    *(bf16x8*)(A + frag * 512 + lane * 8) = out[c];
  }
}

// --------------------------------------------------- B packing (fp32 -> bf16)
// Frag-ordered B (verified R11): frag = ((obn*NT+kt)*8+colg)*2+kk over
// 128-col panels obn (0..7); lane holds B[col=obn*128+colg*16+l15][k...].
__global__ __launch_bounds__(256) void pack_b(
    const float* __restrict__ bw, const float* __restrict__ sw,
    const float* __restrict__ sc, __hip_bfloat16* __restrict__ B) {
  const int tid = threadIdx.x;
  const int lane = tid & 63;
  const int wid = blockIdx.x * 4 + (tid >> 6);   // 0..2047
  const int og = wid >> 5;           // 0..63: o-group of 16
  const int ib32 = wid & 31;         // 0..31: 32-wide i block
  const int obn = og >> 3, colg = og & 7;
  const int l15 = lane & 15, lhi = lane >> 4;
  const int o = og * 16 + l15;
  const int i0 = ib32 * 32 + lhi * 8;

  float bwv[8], scv[8];
  const float* bp = bw + (size_t)o * IN_F + i0;
  const float* sp = sc + (size_t)o * IN_F + i0;
  *(f32x4*)&bwv[0] = *(const f32x4*)bp;
  *(f32x4*)&bwv[4] = *(const f32x4*)(bp + 4);
  *(f32x4*)&scv[0] = *(const f32x4*)sp;
  *(f32x4*)&scv[4] = *(const f32x4*)(sp + 4);

  bf16x8 out[9];
#pragma unroll
  for (int j = 0; j < 8; ++j) {
    out[0][j] = (short)__bfloat16_as_ushort(__float2bfloat16(bwv[j]));
    const float* swp = sw + ((size_t)o * IN_F + i0 + j) * 8;
    float swv[8];
    *(f32x4*)&swv[0] = *(const f32x4*)swp;
    *(f32x4*)&swv[4] = *(const f32x4*)(swp + 4);
#pragma unroll
    for (int c = 0; c < 8; ++c)
      out[c + 1][j] = (short)__bfloat16_as_ushort(__float2bfloat16(swv[c] * scv[j]));
  }

#pragma unroll
  for (int c = 0; c < 9; ++c) {
    int kt = c * 16 + (ib32 >> 1);     // k0 = c*1024 + ib32*32
    int kk = ib32 & 1;
    size_t frag = ((size_t)obn * NT + kt) * 16 + colg * 2 + kk;
    *(bf16x8*)(B + frag * 512 + lane * 8) = out[c];
  }
}

// -------------------------------------------------------------- bf16 GEMM BT
// v12: 256x256 tile, split-K=2, 8 waves @ 128x64 (LDS reads 3 B/C-elem vs
// 4 B at 256x128). 2-slot 128 KB ring staged 1 ahead, ONE barrier/tile,
// frag-ordered A/B (linear LDS, no swizzle), ds_read offset-immediates,
// atomicAdd fp32 epilogue into memset-zeroed C (2 commutative adds/elem).

__device__ __forceinline__ void gld16(const __hip_bfloat16* g, __hip_bfloat16* l) {
  __builtin_amdgcn_global_load_lds((AS1 void*)g, (AS3 void*)l, 16, 0, 0);
}

#define DSRO(dst, addr, IMM)                                               \
  asm volatile("ds_read_b128 %0, %1 offset:" #IMM : "=v"(dst) : "v"(addr))

#define SB __builtin_amdgcn_sched_barrier(0)

#define SLOT_E 32768   // elements per LDS slot (A 32 KB | B 32 KB)
#define SLOT_B 65536

#define READ_A_KK0(d, aA) do {                                             \
    DSRO(d[0], aA, 0);     DSRO(d[1], aA, 2048);                           \
    DSRO(d[2], aA, 4096);  DSRO(d[3], aA, 6144);                           \
    DSRO(d[4], aA, 8192);  DSRO(d[5], aA, 10240);                          \
    DSRO(d[6], aA, 12288); DSRO(d[7], aA, 14336);                          \
  } while (0)
#define READ_A_KK1(d, aA) do {                                             \
    DSRO(d[0], aA, 1024);  DSRO(d[1], aA, 3072);                           \
    DSRO(d[2], aA, 5120);  DSRO(d[3], aA, 7168);                           \
    DSRO(d[4], aA, 9216);  DSRO(d[5], aA, 11264);                          \
    DSRO(d[6], aA, 13312); DSRO(d[7], aA, 15360);                          \
  } while (0)
#define READ_B_KK0(d, bA) do {                                             \
    DSRO(d[0], bA, 0);     DSRO(d[1], bA, 2048);                           \
    DSRO(d[2], bA, 4096);  DSRO(d[3], bA, 6144);                           \
  } while (0)
#define READ_B_KK1(d, bA) do {                                             \
    DSRO(d[0], bA, 1024);  DSRO(d[1], bA, 3072);                           \
    DSRO(d[2], bA, 5120);  DSRO(d[3], bA, 7168);                           \
  } while (0)

#define MFMA_B(sA, sB) do {                                                \
    __builtin_amdgcn_s_setprio(1);                                         \
    _Pragma("unroll")                                                      \
    for (int m_ = 0; m_ < 8; ++m_)                                         \
      _Pragma("unroll")                                                    \
      for (int n_ = 0; n_ < 4; ++n_)                                       \
        acc[m_][n_] = __builtin_amdgcn_mfma_f32_16x16x32_bf16(             \
            sA[m_], sB[n_], acc[m_][n_], 0, 0, 0);                         \
    __builtin_amdgcn_s_setprio(0);                                         \
  } while (0)

// stage next tile (8 x 1KB wave-ops): A 32 KB + B 2x16 KB panels
#define STAGE12(DST) do {                                                  \
    gld16(aGp,          (DST) + dstE);                                     \
    gld16(aGp + 4096,   (DST) + dstE + 4096);                              \
    gld16(aGp + 8192,   (DST) + dstE + 8192);                              \
    gld16(aGp + 12288,  (DST) + dstE + 12288);                             \
    gld16(bGp0,         (DST) + dstE + 16384);                             \
    gld16(bGp0 + 4096,  (DST) + dstE + 20480);                             \
    gld16(bGp1,         (DST) + dstE + 24576);                             \
    gld16(bGp1 + 4096,  (DST) + dstE + 28672);                             \
    aGp += 16384; bGp0 += 8192; bGp1 += 8192;                              \
  } while (0)

// one K-tile; cA/cB = current-slot read bases, nA/nB = next-slot bases
#define TILE_V12(cA, cB, nA, nB, STAGE_, READN_) do {                      \
    READ_A_KK1(ga, cA); READ_B_KK1(gb, cB);        /* lgkm 24 */           \
    STAGE_                                                                 \
    SB;                                                                    \
    asm volatile("s_waitcnt lgkmcnt(12)" ::: "memory"); SB;                \
    MFMA_B(fa, fb);                                                        \
    SB;                                                                    \
    asm volatile("s_waitcnt lgkmcnt(0)" ::: "memory"); SB;                 \
    asm volatile("s_waitcnt vmcnt(0)" ::: "memory"); SB;                   \
    __builtin_amdgcn_s_barrier(); SB;              /* publish next slot */ \
    READN_                                                                 \
    SB;                                                                    \
    MFMA_B(ga, gb);                                                        \
    SB;                                                                    \
  } while (0)

#define READN12(nA, nB) READ_A_KK0(fa, nA); READ_B_KK0(fb, nB);

__global__ __launch_bounds__(512, 2) void gemm_v12(
    const __hip_bfloat16* __restrict__ A, const __hip_bfloat16* __restrict__ B,
    float* __restrict__ C) {
  __shared__ __align__(16) __hip_bfloat16 S[2][SLOT_E];  // 2 x 64 KB

  // bijective XCD swizzle; 4 consecutive L share (bm,khalf) -> same A panel
  const int nwg = gridDim.x;            // (M/256)*8, %8 == 0
  const int q = nwg >> 3;
  const int L = (blockIdx.x & 7) * q + (blockIdx.x >> 3);
  const int bm = L >> 3;
  const int khalf = (L >> 2) & 1;
  const int bn2 = L & 3;                // 256-col block

  const int tid = threadIdx.x;
  const int lane = tid & 63;
  const int wv = tid >> 6;            // 0..7
  const int wm = wv >> 2;             // 0..1 (128-row half)
  const int wn = wv & 3;              // 0..3 (64-col quarter)
  const int l15 = lane & 15, lhi = lane >> 4;

  // ---- staging pointers (per-lane 16 B within each 1 KB frag)
  const int laneE = (wv * 64 + lane) * 8;
  const __hip_bfloat16* aGp =
      A + ((size_t)bm * NT + khalf * NT_H) * A_TILE_E + laneE;
  const __hip_bfloat16* bGp0 =
      B + ((size_t)(2 * bn2) * NT + khalf * NT_H) * B_TILE_E + laneE;
  const __hip_bfloat16* bGp1 =
      B + ((size_t)(2 * bn2 + 1) * NT + khalf * NT_H) * B_TILE_E + laneE;
  __hip_bfloat16* ldsP = &S[0][0];
  const int dstE = wv * 512;

  // ---- fragment read bases (immediates select frag): per slot
  const uint32_t ldsB = (uint32_t)(uintptr_t)(AS3 const void*)&S[0][0];
  const uint32_t aA0 = ldsB + wm * 16384 + lane * 16;
  const uint32_t aA1 = aA0 + SLOT_B;
  const uint32_t bA0 = ldsB + 32768 + (wn >> 1) * 16384 + (wn & 1) * 8192 + lane * 16;
  const uint32_t bA1 = bA0 + SLOT_B;

  f32x4 acc[8][4];
#pragma unroll
  for (int m = 0; m < 8; ++m)
#pragma unroll
    for (int n = 0; n < 4; ++n) acc[m][n] = f32x4{0.f, 0.f, 0.f, 0.f};

  bf16x8 fa[8], fb[4];   // kk0 frags (preloaded)
  bf16x8 ga[8], gb[4];   // kk1 frags

  // ---- prologue: stage tile 0 -> slot0; publish; preload kk0(0)
  STAGE12(ldsP);
  asm volatile("s_waitcnt vmcnt(0)" ::: "memory");
  SB;
  __builtin_amdgcn_s_barrier();
  SB;
  READ_A_KK0(fa, aA0); READ_B_KK0(fb, bA0);        // lgkm 12
  SB;

#pragma unroll 1
  for (int tt = 0; tt < (NT_H - 2) / 2; ++tt) {    // t = 0..69
    TILE_V12(aA0, bA0, aA1, bA1, STAGE12(ldsP + SLOT_E);, READN12(aA1, bA1));
    TILE_V12(aA1, bA1, aA0, bA0, STAGE12(ldsP);,          READN12(aA0, bA0));
  }
  // t = 70: stage tile 71 -> slot1
  TILE_V12(aA0, bA0, aA1, bA1, STAGE12(ldsP + SLOT_E);, READN12(aA1, bA1));
  // t = 71: last
  TILE_V12(aA1, bA1, aA0, bA0, ;, ;);

  // ---- epilogue: atomicAdd into C (split-K partner adds the other half)
  // C/D mapping col = lane&15, row = (lane>>4)*4 + reg  [m89-verified]
#pragma unroll
  for (int m = 0; m < 8; ++m)
#pragma unroll
    for (int n = 0; n < 4; ++n) {
      int col = bn2 * 256 + (wn >> 1) * 128 + (wn & 1) * 64 + n * 16 + l15;
      int row0 = bm * 256 + wm * 128 + m * 16 + lhi * 4;
#pragma unroll
      for (int j = 0; j < 4; ++j)
        atomicAdd(&C[(size_t)(row0 + j) * OUT_F + col], acc[m][n][j]);
    }
}

// ------------------------------------------------ naive fallback (insurance)
__global__ __launch_bounds__(256) void kan_naive(
    const float* __restrict__ x, const float* __restrict__ grid,
    const float* __restrict__ bw, const float* __restrict__ sw,
    const float* __restrict__ sc, float* __restrict__ out) {
  __shared__ float s_act[IN_F];
  __shared__ float s_bas[IN_F * 8];
  int n = blockIdx.x;
  for (int i = threadIdx.x; i < IN_F; i += 256) {
    float xv = x[(size_t)n * IN_F + i];
    float g[12];
    const float* gp = grid + i * 12;
#pragma unroll
    for (int t = 0; t < 12; ++t) g[t] = gp[t];
    float b[11];
#pragma unroll
    for (int j = 0; j < 11; ++j)
      b[j] = (xv >= g[j] && xv < g[j + 1]) ? 1.0f : 0.0f;
#pragma unroll
    for (int k = 1; k <= 3; ++k)
#pragma unroll
      for (int j = 0; j < 11 - k; ++j) {
        float left = (xv - g[j]) / (g[j + k] - g[j]);
        float right = (g[j + k + 1] - xv) / (g[j + k + 1] - g[j + 1]);
        b[j] = left * b[j] + right * b[j + 1];
      }
    s_act[i] = xv / (1.0f + __expf(-xv));
#pragma unroll
    for (int c = 0; c < 8; ++c) s_bas[i * 8 + c] = b[c];
  }
  __syncthreads();
  for (int o = threadIdx.x; o < OUT_F; o += 256) {
    float acc = 0.f;
    const float* bwo = bw + (size_t)o * IN_F;
    const float* swo = sw + (size_t)o * IN_F * 8;
    const float* sco = sc + (size_t)o * IN_F;
    for (int i = 0; i < IN_F; ++i) {
      acc += s_act[i] * bwo[i];
      float p = 0.f;
#pragma unroll
      for (int c = 0; c < 8; ++c) p += s_bas[i * 8 + c] * swo[i * 8 + c];
      acc += p * sco[i];
    }
    out[(size_t)n * OUT_F + o] = acc;
  }
}

// ---------------------------------------------------------------- launch
extern "C" void kernel_launch(void* const* d_in, const int* in_sizes, int n_in,
                              void* d_out, int out_size, void* d_ws, size_t ws_size,
                              hipStream_t stream) {
  const float* x  = (const float*)d_in[0];
  const float* grid = (const float*)d_in[1];
  const float* bw = (const float*)d_in[2];
  const float* sw = (const float*)d_in[3];
  const float* sc = (const float*)d_in[4];
  float* out = (float*)d_out;

  const size_t Bbytes = (size_t)OUT_F * KTOT * 2;   // 18.9 MB
  const size_t rowBytes = (size_t)KTOT * 2;         // 18 KB / A-row

  if (ws_size >= Bbytes + 256 * rowBytes) {
    __hip_bfloat16* Bp = (__hip_bfloat16*)d_ws;
    __hip_bfloat16* Ap = (__hip_bfloat16*)((char*)d_ws + Bbytes);
    size_t arows = (ws_size - Bbytes) / rowBytes;
    int chunk = (int)((arows / 256) * 256);
    if (chunk > M_ROWS) chunk = M_ROWS;

    hipMemsetAsync(d_out, 0, (size_t)out_size * sizeof(float), stream);
    pack_b<<<OUT_F * 128 / 256, 256, 0, stream>>>(bw, sw, sc, Bp);
    for (int r0 = 0; r0 < M_ROWS; r0 += chunk) {
      int rows = M_ROWS - r0 < chunk ? M_ROWS - r0 : chunk;   // multiple of 256
      expand_a<<<(rows / 16) * 8, 256, 0, stream>>>(x, grid, Ap, r0, rows);
      gemm_v12<<<(rows / 256) * 8, 512, 0, stream>>>(Ap, Bp, out + (size_t)r0 * OUT_F);
    }
  } else {
    kan_naive<<<M_ROWS, 256, 0, stream>>>(x, grid, bw, sw, sc, out);
  }
}